// Round 12
// baseline (61.458 us; speedup 1.0000x reference)
//
#include <hip/hip_runtime.h>

// LRFGraphConv: out[v] = ((nbr_sum[v] - deg[v]*verts[v]) @ lrf[v]) @ W^T + maxN*b
//
// R12: A/B evidence (R9 global-atomic scatter == R11 LDS-sort scatter == ~59us)
// says accum (NR=196 blocks = 0.77/CU) is the hog. Shrink ranges 4x:
//   RSIZE=64 -> NR=782 accum blocks (3/CU), dense per-range segments.
//  K0 zero: clear 1024 cursors.
//  K1 scatter (R9-style): per-block LDS count over 782 ranges, one independent
//     global atomic-return per (block,range), LDS rank cursors, guarded write.
//  K2 accum: block r owns 64 verts; dense read of its segment, fp32 LDS
//     accumulation, writes nbrdeg + rmax[r] (plain store).
//  K3 lrf_out: reduce rmax[NR] in-block, rotate+project, float4 writes.

#define RBITS 6
#define RSIZE 64        // vertices per range
#define NRMAX 1024      // array bound (NR = 782)
#define CAPR  1536      // pairs capacity per range (mean 1024, +6 sigma)
#define STHR  512

__global__ __launch_bounds__(256)
void zero_kernel(unsigned* __restrict__ cursor) {
    int t = blockIdx.x * 256 + threadIdx.x;
    if (t < NRMAX) cursor[t] = 0u;
}

__global__ __launch_bounds__(512)
void scatter_kernel(const int* __restrict__ edges,
                    unsigned* __restrict__ cursor,   // [NRMAX] zeroed
                    unsigned* __restrict__ pairs,    // [NR][CAPR]
                    int E, int NR) {
    __shared__ unsigned cnt[NRMAX];
    __shared__ unsigned cur[NRMAX];
    __shared__ unsigned bas[NRMAX];
    const int t = threadIdx.x;
    for (int i = t; i < NRMAX; i += STHR) { cnt[i] = 0u; cur[i] = 0u; }
    __syncthreads();

    int i4 = blockIdx.x * STHR + t;
    int e0 = 2 * i4, e1 = e0 + 1;
    int rr[4]; unsigned pk[4]; int np = 0;
    if (e1 < E) {
        int4 e = ((const int4*)edges)[i4];
        rr[0] = e.x >> RBITS; pk[0] = ((unsigned)e.y << RBITS) | ((unsigned)e.x & (RSIZE - 1));
        rr[1] = e.y >> RBITS; pk[1] = ((unsigned)e.x << RBITS) | ((unsigned)e.y & (RSIZE - 1));
        rr[2] = e.z >> RBITS; pk[2] = ((unsigned)e.w << RBITS) | ((unsigned)e.z & (RSIZE - 1));
        rr[3] = e.w >> RBITS; pk[3] = ((unsigned)e.z << RBITS) | ((unsigned)e.w & (RSIZE - 1));
        np = 4;
    } else if (e0 < E) {
        int2 e = ((const int2*)edges)[e0];
        rr[0] = e.x >> RBITS; pk[0] = ((unsigned)e.y << RBITS) | ((unsigned)e.x & (RSIZE - 1));
        rr[1] = e.y >> RBITS; pk[1] = ((unsigned)e.x << RBITS) | ((unsigned)e.y & (RSIZE - 1));
        np = 2;
    }

    #pragma unroll
    for (int j = 0; j < 4; ++j)
        if (j < np) atomicAdd(&cnt[rr[j]], 1u);
    __syncthreads();

    // one independent global atomic-return per nonempty (block, range)
    for (int r = t; r < NR; r += STHR) {
        unsigned c = cnt[r];
        bas[r] = c ? atomicAdd(&cursor[r], c) : 0u;
    }
    __syncthreads();

    #pragma unroll
    for (int j = 0; j < 4; ++j)
        if (j < np) {
            int r = rr[j];
            unsigned s = bas[r] + atomicAdd(&cur[r], 1u);
            if (s < CAPR) pairs[(unsigned)r * CAPR + s] = pk[j];
        }
}

__global__ __launch_bounds__(256)
void accum_kernel(const float* __restrict__ verts,
                  const unsigned* __restrict__ pairs,
                  const unsigned* __restrict__ cursor,
                  float4* __restrict__ nbrdeg,
                  float* __restrict__ rmax,
                  int V) {
    __shared__ float4 acc[RSIZE];
    __shared__ float wm[4];
    const int r = blockIdx.x, t = threadIdx.x;
    if (t < RSIZE) acc[t] = make_float4(0.f, 0.f, 0.f, 0.f);
    __syncthreads();

    unsigned n = cursor[r];
    if (n > CAPR) n = CAPR;
    const unsigned* seg = pairs + (unsigned)r * CAPR;
    for (unsigned p = t; p < n; p += 256) {
        unsigned pk = seg[p];
        int nb = (int)(pk >> RBITS);
        int cl = (int)(pk & (RSIZE - 1));
        float* ap = (float*)&acc[cl];
        atomicAdd(ap + 0, verts[3 * nb + 0]);
        atomicAdd(ap + 1, verts[3 * nb + 1]);
        atomicAdd(ap + 2, verts[3 * nb + 2]);
        atomicAdd(ap + 3, 1.f);
    }
    __syncthreads();

    int v0 = r << RBITS;
    int nv = min(RSIZE, V - v0);
    float d = 0.f;
    if (t < nv) { float4 a4 = acc[t]; nbrdeg[v0 + t] = a4; d = a4.w; }
    #pragma unroll
    for (int off = 32; off > 0; off >>= 1)
        d = fmaxf(d, __shfl_down(d, off, 64));
    if ((t & 63) == 0) wm[t >> 6] = d;
    __syncthreads();
    if (t == 0)
        rmax[r] = fmaxf(fmaxf(wm[0], wm[1]), fmaxf(wm[2], wm[3]));
}

__global__ __launch_bounds__(256)
void lrf_out(const float* __restrict__ verts,
             const float* __restrict__ lrf,
             const float4* __restrict__ W4,     // W as float4[96]
             const float4* __restrict__ bias4,  // bias as float4[32]
             const float4* __restrict__ nbrdeg,
             const float* __restrict__ rmax,
             float4* __restrict__ out4,         // out as float4[V*32]
             int V, int NR) {
    __shared__ float ms[4];
    const int t = threadIdx.x;
    float m = 0.f;
    for (int i = t; i < NR; i += 256) m = fmaxf(m, rmax[i]);
    #pragma unroll
    for (int off = 32; off > 0; off >>= 1)
        m = fmaxf(m, __shfl_down(m, off, 64));
    if ((t & 63) == 0) ms[t >> 6] = m;
    __syncthreads();
    float mx = fmaxf(fmaxf(ms[0], ms[1]), fmaxf(ms[2], ms[3]));

    int item = blockIdx.x * 256 + t;
    if (item >= V * 32) return;
    int v = item >> 5;
    int q = item & 31;

    float4 nd = nbrdeg[v];
    float s0 = nd.x - nd.w * verts[3 * v + 0];
    float s1 = nd.y - nd.w * verts[3 * v + 1];
    float s2 = nd.z - nd.w * verts[3 * v + 2];

    const float* L = lrf + (size_t)9 * v;   // lrf[v,j,k] row-major
    float r0 = s0 * L[0] + s1 * L[3] + s2 * L[6];
    float r1 = s0 * L[1] + s1 * L[4] + s2 * L[7];
    float r2 = s0 * L[2] + s1 * L[5] + s2 * L[8];

    float4 w0 = W4[3 * q + 0];
    float4 w1 = W4[3 * q + 1];
    float4 w2 = W4[3 * q + 2];
    float4 bv = bias4[q];

    float4 o;
    o.x = r0 * w0.x + r1 * w0.y + r2 * w0.z + mx * bv.x;
    o.y = r0 * w0.w + r1 * w1.x + r2 * w1.y + mx * bv.y;
    o.z = r0 * w1.z + r1 * w1.w + r2 * w2.x + mx * bv.z;
    o.w = r0 * w2.y + r1 * w2.z + r2 * w2.w + mx * bv.w;
    out4[item] = o;
}

extern "C" void kernel_launch(void* const* d_in, const int* in_sizes, int n_in,
                              void* d_out, int out_size, void* d_ws, size_t ws_size,
                              hipStream_t stream) {
    const float* verts = (const float*)d_in[0];
    const int*   edges = (const int*)d_in[1];
    const float* lrf   = (const float*)d_in[2];
    const float* W     = (const float*)d_in[3];
    const float* bias  = (const float*)d_in[4];

    int V = in_sizes[0] / 3;
    int E = in_sizes[1] / 2;
    int NR = (V + RSIZE - 1) >> RBITS;          // 782 ranges
    int Ni4 = (E + 1) / 2;
    int NB = (Ni4 + STHR - 1) / STHR;           // 391 scatter blocks

    // ---- workspace layout ----
    // [cursor NRMAX u32][rmax NRMAX f32][pairs NRMAX*CAPR u32][nbrdeg V f4]
    char* ws = (char*)d_ws;
    size_t off = 0;
    unsigned* cursor = (unsigned*)(ws + off); off += (size_t)NRMAX * 4;
    float*    rmax   = (float*)(ws + off);    off += (size_t)NRMAX * 4;
    unsigned* pairs  = (unsigned*)(ws + off); off += (size_t)NRMAX * CAPR * 4;
    off = (off + 15) & ~(size_t)15;
    float4*   nbrdeg = (float4*)(ws + off);

    zero_kernel<<<(NRMAX + 255) / 256, 256, 0, stream>>>(cursor);

    scatter_kernel<<<NB, STHR, 0, stream>>>(edges, cursor, pairs, E, NR);

    accum_kernel<<<NR, 256, 0, stream>>>(verts, pairs, cursor, nbrdeg, rmax, V);

    int ob = (V * 32 + 255) / 256;
    lrf_out<<<ob, 256, 0, stream>>>(verts, lrf, (const float4*)W,
                                    (const float4*)bias, nbrdeg, rmax,
                                    (float4*)d_out, V, NR);
}